// Round 2
// baseline (926.820 us; speedup 1.0000x reference)
//
#include <hip/hip_runtime.h>
#include <cstdint>
#include <cstddef>

typedef unsigned short ushort_t;
typedef __attribute__((ext_vector_type(8))) short short8;
typedef __attribute__((ext_vector_type(4))) short short4v;
typedef __attribute__((ext_vector_type(4))) float floatx4;

__device__ __forceinline__ float b2f(ushort_t u) {
    unsigned v = ((unsigned)u) << 16;
    return __builtin_bit_cast(float, v);
}
__device__ __forceinline__ float b2fs(short s) { return b2f((ushort_t)s); }
__device__ __forceinline__ ushort_t f2b(float f) {
    unsigned u = __builtin_bit_cast(unsigned, f);
    u += 0x7fffu + ((u >> 16) & 1u);   // RNE
    return (ushort_t)(u >> 16);
}

// async global->LDS, 16B per lane; lds base must be wave-uniform (HW adds lane*16)
__device__ __forceinline__ void load_lds16(const ushort_t* g, ushort_t* l) {
    __builtin_amdgcn_global_load_lds(
        (const __attribute__((address_space(1))) void*)g,
        (__attribute__((address_space(3))) void*)l, 16, 0, 0);
}

// ---------------------------------------------------------------------------
// Strip GEMM, K=256, A panel in registers. B double-buffered as 64-col x 256-k
// half-tiles (2 x 32KB LDS). Pipeline: issue stage(p+1) -> compute(p) ->
// counted s_waitcnt vmcnt(8) + raw s_barrier (loads precede stores in the
// queue, so vmcnt(8) drains exactly the 8 stage loads; epilogue stores stay
// in flight). MFMA operands SWAPPED (mfma(bf,af)) so the output lane mapping
// is lane&15 = m-row, quad*4+reg = n-col -> 8B vector stores.
// ---------------------------------------------------------------------------
template <int NT, bool A_F32, bool HAS_BIAS, bool DO_SILU>
__global__ __launch_bounds__(256, 2) void gemm_areg(
    const void* __restrict__ Ap, const ushort_t* __restrict__ BT,
    const float* __restrict__ bias, ushort_t* __restrict__ out)
{
    constexpr int K = 256;
    constexpr int ldN = NT * 128;
    constexpr int NH = NT * 2;                          // 64-col halves
    __shared__ __align__(16) ushort_t Bs[2][64 * 256];  // 2 x 32 KB, swizzled

    const int tid = threadIdx.x;
    const int w = tid >> 6, lane = tid & 63;
    const int wm = w >> 1, wn = w & 1;
    const int quad = lane >> 4, r = lane & 15;
    const size_t m0 = (size_t)blockIdx.x * 128;

    // staging constants: 8 insts/wave cover 16 rows (2 rows per inst)
    const int srow_off = w * 2 + (lane >> 5);           // == row & 7
    const int sslot = (lane & 31) ^ srow_off;
    const int rsw = (r & 7) << 3;                       // read-side XOR (ushorts)

#define STAGE_H(h)                                                        \
    {                                                                     \
        const int h_ = (h);                                               \
        _Pragma("unroll")                                                 \
        for (int i_ = 0; i_ < 8; ++i_) {                                  \
            int row_ = i_ * 8 + srow_off;                                 \
            load_lds16(BT + (size_t)(h_ * 64 + row_) * K + sslot * 8,     \
                       &Bs[h_ & 1][(i_ * 8 + w * 2) * 256]);              \
        }                                                                 \
    }

    STAGE_H(0);

    // ---- A panel -> registers (rows wm*64+mt*16+r, k = kk*32+quad*8) ----
    short8 af[4][8];
    if (A_F32) {
        const float* A = (const float*)Ap;
#pragma unroll
        for (int mt = 0; mt < 4; ++mt) {
            const float* rp = A + (m0 + wm * 64 + mt * 16 + r) * K + quad * 8;
#pragma unroll
            for (int kk = 0; kk < 8; ++kk) {
                float4 a = *(const float4*)(rp + kk * 32);
                float4 b = *(const float4*)(rp + kk * 32 + 4);
                short8 o;
                o[0] = (short)f2b(a.x); o[1] = (short)f2b(a.y);
                o[2] = (short)f2b(a.z); o[3] = (short)f2b(a.w);
                o[4] = (short)f2b(b.x); o[5] = (short)f2b(b.y);
                o[6] = (short)f2b(b.z); o[7] = (short)f2b(b.w);
                af[mt][kk] = o;
            }
        }
    } else {
        const ushort_t* A = (const ushort_t*)Ap;
#pragma unroll
        for (int mt = 0; mt < 4; ++mt) {
            const ushort_t* rp = A + (m0 + wm * 64 + mt * 16 + r) * K + quad * 8;
#pragma unroll
            for (int kk = 0; kk < 8; ++kk)
                af[mt][kk] = *(const short8*)(rp + kk * 32);
        }
    }

    asm volatile("s_waitcnt vmcnt(0)" ::: "memory");
    __builtin_amdgcn_s_barrier();

    for (int p = 0; p < NH; ++p) {
        if (p + 1 < NH) STAGE_H(p + 1);

        floatx4 acc[2][4];
#pragma unroll
        for (int nt = 0; nt < 2; ++nt)
#pragma unroll
            for (int mt = 0; mt < 4; ++mt)
#pragma unroll
                for (int rg = 0; rg < 4; ++rg) acc[nt][mt][rg] = 0.f;

#pragma unroll
        for (int kk = 0; kk < 8; ++kk) {
            const int koff = (kk * 32 + quad * 8) ^ rsw;
#pragma unroll
            for (int nt = 0; nt < 2; ++nt) {
                int cl = wn * 32 + nt * 16 + r;          // cl&7 == r&7
                short8 bf_ = *(const short8*)(&Bs[p & 1][cl * 256 + koff]);
#pragma unroll
                for (int mt = 0; mt < 4; ++mt)
                    acc[nt][mt] = __builtin_amdgcn_mfma_f32_16x16x32_bf16(
                        bf_, af[mt][kk], acc[nt][mt], 0, 0, 0);
            }
        }
        // epilogue: lane owns row = m0+wm*64+mt*16+r, 4 consecutive cols
#pragma unroll
        for (int nt = 0; nt < 2; ++nt) {
            const int colb = p * 64 + wn * 32 + nt * 16 + quad * 4;
            float b4[4] = {0.f, 0.f, 0.f, 0.f};
            if (HAS_BIAS) {
                float4 bb = *(const float4*)(bias + colb);
                b4[0] = bb.x; b4[1] = bb.y; b4[2] = bb.z; b4[3] = bb.w;
            }
#pragma unroll
            for (int mt = 0; mt < 4; ++mt) {
                size_t row = m0 + wm * 64 + mt * 16 + r;
                short4v ov;
#pragma unroll
                for (int rg = 0; rg < 4; ++rg) {
                    float v = acc[nt][mt][rg] + b4[rg];
                    if (DO_SILU) v = v / (1.f + __expf(-v));
                    ov[rg] = (short)f2b(v);
                }
                *(short4v*)(out + row * ldN + colb) = ov;
            }
        }
        // loads (8) were issued before this iter's stores -> vmcnt(8) drains
        // exactly the stage loads; stores may remain in flight.
        asm volatile("s_waitcnt vmcnt(8)" ::: "memory");
        __builtin_amdgcn_s_barrier();
    }
#undef STAGE_H
}

// ---------------------------------------------------------------------------
// Wide GEMM for FF2: K=1024, N=256. 32-k chunk double-buffer (2x8KB A,
// 2x16KB B = 48KB), counted-pipeline: stage(c+1) -> compute(c) -> vmcnt(0)
// (loads had a full compute phase in flight) + raw barrier. Swapped MFMA
// epilogue -> 32 x 8B stores. Swizzle: 16B slot ^= row&3 (64B rows).
// ---------------------------------------------------------------------------
__global__ __launch_bounds__(256, 2) void gemm_wide(
    const ushort_t* __restrict__ A, const ushort_t* __restrict__ BT,
    ushort_t* __restrict__ out)
{
    constexpr int K = 1024, N = 256;
    __shared__ __align__(16) ushort_t As[2][128 * 32];   // 2 x 8 KB
    __shared__ __align__(16) ushort_t Bs[2][256 * 32];   // 2 x 16 KB

    const int tid = threadIdx.x;
    const int w = tid >> 6, lane = tid & 63;
    const int wm = w >> 1, wn = w & 1;
    const int quad = lane >> 4, r = lane & 15;
    const size_t m0 = (size_t)blockIdx.x * 128;

    // staging: one inst covers 16 rows x 64B; slot(16B) ^= row&3
    const int srow = lane >> 2;                    // 0..15
    const int sslot = (lane & 3) ^ (srow & 3);

#define STAGE_C(c)                                                        \
    {                                                                     \
        const int c_ = (c);                                               \
        _Pragma("unroll")                                                 \
        for (int i_ = 0; i_ < 2; ++i_) {                                  \
            int rb_ = (w * 2 + i_) * 16;                                  \
            load_lds16(A + (m0 + rb_ + srow) * K + c_ * 32 + sslot * 8,   \
                       &As[c_ & 1][rb_ * 32]);                            \
        }                                                                 \
        _Pragma("unroll")                                                 \
        for (int i_ = 0; i_ < 4; ++i_) {                                  \
            int rb_ = (w * 4 + i_) * 16;                                  \
            load_lds16(BT + (size_t)(rb_ + srow) * K + c_ * 32 + sslot * 8,\
                       &Bs[c_ & 1][rb_ * 32]);                            \
        }                                                                 \
    }

    floatx4 acc[8][4];
#pragma unroll
    for (int nt = 0; nt < 8; ++nt)
#pragma unroll
        for (int mt = 0; mt < 4; ++mt)
#pragma unroll
            for (int rg = 0; rg < 4; ++rg) acc[nt][mt][rg] = 0.f;

    STAGE_C(0);
    asm volatile("s_waitcnt vmcnt(0)" ::: "memory");
    __builtin_amdgcn_s_barrier();

    const int ko = (quad ^ (r & 3)) * 8;           // swizzled 32-k slot

    for (int c = 0; c < K / 32; ++c) {
        if (c + 1 < K / 32) STAGE_C(c + 1);

        short8 af_[4];
#pragma unroll
        for (int mt = 0; mt < 4; ++mt)
            af_[mt] = *(const short8*)(&As[c & 1][(wm * 64 + mt * 16 + r) * 32 + ko]);
#pragma unroll
        for (int nt = 0; nt < 8; ++nt) {
            short8 bf_ = *(const short8*)(&Bs[c & 1][(wn * 128 + nt * 16 + r) * 32 + ko]);
#pragma unroll
            for (int mt = 0; mt < 4; ++mt)
                acc[nt][mt] = __builtin_amdgcn_mfma_f32_16x16x32_bf16(
                    bf_, af_[mt], acc[nt][mt], 0, 0, 0);
        }
        asm volatile("s_waitcnt vmcnt(0)" ::: "memory");
        __builtin_amdgcn_s_barrier();
    }
#undef STAGE_C

    // epilogue: row = m0+wm*64+mt*16+r; cols wn*128+nt*16+quad*4+{0..3}
#pragma unroll
    for (int nt = 0; nt < 8; ++nt) {
        const int colb = wn * 128 + nt * 16 + quad * 4;
#pragma unroll
        for (int mt = 0; mt < 4; ++mt) {
            size_t row = m0 + wm * 64 + mt * 16 + r;
            short4v ov;
#pragma unroll
            for (int rg = 0; rg < 4; ++rg) ov[rg] = (short)f2b(acc[nt][mt][rg]);
            *(short4v*)(out + row * N + colb) = ov;
        }
    }
}

// ---------------------------------------------------------------------------
// LayerNorm over rows of 256: out = LN(y [+ res]) * g + b.  1 wave per row.
// ---------------------------------------------------------------------------
template <bool OUT_F32>
__global__ __launch_bounds__(256) void ln_kernel(
    const ushort_t* __restrict__ y, const ushort_t* __restrict__ res,
    const float* __restrict__ g, const float* __restrict__ b,
    void* __restrict__ outv)
{
    const int w = threadIdx.x >> 6;
    const int lane = threadIdx.x & 63;
    const size_t row = (size_t)blockIdx.x * 4 + w;
    const size_t base = row * 256 + lane * 4;

    short4v vy = *(const short4v*)(y + base);
    float v[4];
#pragma unroll
    for (int j = 0; j < 4; ++j) v[j] = b2fs(vy[j]);
    if (res) {
        short4v vr = *(const short4v*)(res + base);
#pragma unroll
        for (int j = 0; j < 4; ++j) v[j] += b2fs(vr[j]);
    }
    float s = v[0] + v[1] + v[2] + v[3];
    float sq = v[0] * v[0] + v[1] * v[1] + v[2] * v[2] + v[3] * v[3];
#pragma unroll
    for (int off = 32; off > 0; off >>= 1) {
        s += __shfl_xor(s, off, 64);
        sq += __shfl_xor(sq, off, 64);
    }
    float mean = s * (1.f / 256.f);
    float var = sq * (1.f / 256.f) - mean * mean;
    float rstd = rsqrtf(var + 1e-5f);
    if (OUT_F32) {
        float4 ov;
        int col = lane * 4;
        ov.x = (v[0] - mean) * rstd * g[col + 0] + b[col + 0];
        ov.y = (v[1] - mean) * rstd * g[col + 1] + b[col + 1];
        ov.z = (v[2] - mean) * rstd * g[col + 2] + b[col + 2];
        ov.w = (v[3] - mean) * rstd * g[col + 3] + b[col + 3];
        *(float4*)((float*)outv + base) = ov;
    } else {
        short4v ov;
#pragma unroll
        for (int j = 0; j < 4; ++j) {
            int col = lane * 4 + j;
            float o = (v[j] - mean) * rstd * g[col] + b[col];
            ov[j] = (short)f2b(o);
        }
        *(short4v*)((ushort_t*)outv + base) = ov;
    }
}

// ---------------------------------------------------------------------------
// Attention: one wave per token (8 positions x 8 heads x d=32).
// ---------------------------------------------------------------------------
__global__ __launch_bounds__(256) void attn_kernel(
    const ushort_t* __restrict__ qkv,
    const float* __restrict__ pos1, const float* __restrict__ pos2,
    const float* __restrict__ Wpos, const float* __restrict__ Wbias,
    ushort_t* __restrict__ att_out)
{
    __shared__ __align__(16) ushort_t qkv_s[4][8 * 768];
    __shared__ float bias_s[4][8][8];
    __shared__ float wpos_s[128];
    __shared__ float wbias_s[256];

    const int tid = threadIdx.x;
    if (tid < 128) wpos_s[tid] = Wpos[tid];
    wbias_s[tid] = Wbias[tid];

    const int w = tid >> 6;
    const int lane = tid & 63;
    const int tok = blockIdx.x * 4 + w;

    const ushort_t* src = qkv + (size_t)tok * 8 * 768;
    for (int c = lane; c < 768; c += 64)
        *(short8*)(qkv_s[w] + c * 8) = *(const short8*)(src + c * 8);
    __syncthreads();

    {   // positional bias: lane = j*8 + h
        const int j = lane >> 3, h = lane & 7;
        const size_t pbase = ((size_t)tok * 8 + j) * 2;
        float p0 = pos1[pbase], p1 = pos1[pbase + 1];
        float p2 = pos2[pbase], p3 = pos2[pbase + 1];
        float acc = 0.f;
#pragma unroll
        for (int p = 0; p < 32; ++p) {
            float e = p0 * wpos_s[p] + p1 * wpos_s[32 + p] + p2 * wpos_s[64 + p] + p3 * wpos_s[96 + p];
            e = e / (1.f + __expf(-e));
            acc += e * wbias_s[p * 8 + h];
        }
        bias_s[w][j][h] = acc;
    }
    __syncthreads();

    const int i = lane >> 3, h = lane & 7;
    const ushort_t* qrow = qkv_s[w] + i * 768 + h * 32;
    float q[32];
#pragma unroll
    for (int c = 0; c < 4; ++c) {
        short8 t8 = *(const short8*)(qrow + c * 8);
#pragma unroll
        for (int e = 0; e < 8; ++e) q[c * 8 + e] = b2fs(t8[e]);
    }
    float s[8];
#pragma unroll
    for (int jj = 0; jj < 8; ++jj) {
        const ushort_t* krow = qkv_s[w] + jj * 768 + 256 + h * 32;
        float d = 0.f;
#pragma unroll
        for (int c = 0; c < 4; ++c) {
            short8 t8 = *(const short8*)(krow + c * 8);
#pragma unroll
            for (int e = 0; e < 8; ++e) d += q[c * 8 + e] * b2fs(t8[e]);
        }
        s[jj] = d * 0.17677669529663688f + bias_s[w][jj][h];
    }
    float mx = s[0];
#pragma unroll
    for (int jj = 1; jj < 8; ++jj) mx = fmaxf(mx, s[jj]);
    float l = 0.f;
#pragma unroll
    for (int jj = 0; jj < 8; ++jj) { s[jj] = __expf(s[jj] - mx); l += s[jj]; }
    float rl = 1.f / l;
    float o[32];
#pragma unroll
    for (int e = 0; e < 32; ++e) o[e] = 0.f;
#pragma unroll
    for (int jj = 0; jj < 8; ++jj) {
        float p = s[jj] * rl;
        const ushort_t* vrow = qkv_s[w] + jj * 768 + 512 + h * 32;
#pragma unroll
        for (int c = 0; c < 4; ++c) {
            short8 t8 = *(const short8*)(vrow + c * 8);
#pragma unroll
            for (int e = 0; e < 8; ++e) o[c * 8 + e] += p * b2fs(t8[e]);
        }
    }
    ushort_t* orow = att_out + ((size_t)tok * 8 + i) * 256 + h * 32;
#pragma unroll
    for (int c = 0; c < 4; ++c) {
        short8 t8;
#pragma unroll
        for (int e = 0; e < 8; ++e) t8[e] = (short)f2b(o[c * 8 + e]);
        *(short8*)(orow + c * 8) = t8;
    }
}

// ---------------------------------------------------------------------------
__global__ void transpose_kernel(const float* __restrict__ in,
                                 ushort_t* __restrict__ out, int K, int N)
{
    int idx = blockIdx.x * 256 + threadIdx.x;
    if (idx < K * N) {
        int k = idx / N, n = idx % N;
        out[n * K + k] = f2b(in[idx]);
    }
}

__global__ void pack_bias_kernel(const float* a, const float* b,
                                 const float* c, float* out)
{
    int t = blockIdx.x * 256 + threadIdx.x;
    if (t < 256) out[t] = a[t];
    else if (t < 512) out[t] = b[t - 256];
    else if (t < 768) out[t] = c[t - 512];
}

// ---------------------------------------------------------------------------
extern "C" void kernel_launch(void* const* d_in, const int* in_sizes, int n_in,
                              void* d_out, int out_size, void* d_ws, size_t ws_size,
                              hipStream_t stream)
{
    const float* x     = (const float*)d_in[0];
    const float* pos1  = (const float*)d_in[1];
    const float* pos2  = (const float*)d_in[2];
    const float* W_in  = (const float*)d_in[3];
    const float* g_in  = (const float*)d_in[4];
    const float* b_in  = (const float*)d_in[5];
    const float* Wq    = (const float*)d_in[6];
    const float* bq    = (const float*)d_in[7];
    const float* Wk    = (const float*)d_in[8];
    const float* bk    = (const float*)d_in[9];
    const float* Wv    = (const float*)d_in[10];
    const float* bv    = (const float*)d_in[11];
    const float* Wo    = (const float*)d_in[12];
    const float* bo    = (const float*)d_in[13];
    const float* W_pos = (const float*)d_in[14];
    const float* W_bias= (const float*)d_in[15];
    const float* W_ff1 = (const float*)d_in[16];
    const float* W_ff2 = (const float*)d_in[17];
    const float* g1    = (const float*)d_in[18];
    const float* b1    = (const float*)d_in[19];
    const float* g2    = (const float*)d_in[20];
    const float* b2    = (const float*)d_in[21];

    const int M = in_sizes[0] / 256;   // 131072 rows (b,n,nh)
    const int ntok = M / 8;            // 16384 tokens

    // ws: 2MB header (bf16 weights^T + fp32 qkv bias) then big buffers
    ushort_t* ws    = (ushort_t*)d_ws;
    ushort_t* WinT  = ws;              // 256x256
    ushort_t* WqkvT = ws + 65536;      // 768x256
    ushort_t* WoT   = ws + 262144;     // 256x256
    ushort_t* Wff1T = ws + 327680;     // 1024x256
    ushort_t* Wff2T = ws + 589824;     // 256x1024
    float*    bqkv  = (float*)(ws + 851968);                    // 768 fp32
    ushort_t* bufA  = (ushort_t*)((char*)d_ws + (2ull << 20));  // M*256
    ushort_t* bufB  = bufA + (size_t)M * 256;                   // M*256
    ushort_t* bufC  = bufB + (size_t)M * 256;                   // M*1024

    transpose_kernel<<<256, 256, 0, stream>>>(W_in, WinT, 256, 256);
    transpose_kernel<<<256, 256, 0, stream>>>(Wq, WqkvT, 256, 256);
    transpose_kernel<<<256, 256, 0, stream>>>(Wk, WqkvT + 65536, 256, 256);
    transpose_kernel<<<256, 256, 0, stream>>>(Wv, WqkvT + 131072, 256, 256);
    transpose_kernel<<<256, 256, 0, stream>>>(Wo, WoT, 256, 256);
    transpose_kernel<<<1024, 256, 0, stream>>>(W_ff1, Wff1T, 256, 1024);
    transpose_kernel<<<1024, 256, 0, stream>>>(W_ff2, Wff2T, 1024, 256);
    pack_bias_kernel<<<3, 256, 0, stream>>>(bq, bk, bv, bqkv);

    dim3 blk(256);
    // y = x @ W_in      (fp32 A fused-converted into A-registers)
    gemm_areg<2, true, false, false><<<M / 128, blk, 0, stream>>>(x, WinT, nullptr, bufA);
    // t = LN(y)
    ln_kernel<false><<<M / 4, blk, 0, stream>>>(bufA, nullptr, g_in, b_in, bufB);
    // qkv = t @ [Wq|Wk|Wv] + [bq|bk|bv]
    gemm_areg<6, false, true, false><<<M / 128, blk, 0, stream>>>(bufB, WqkvT, bqkv, bufC);
    // att_out = attention(qkv, pos)
    attn_kernel<<<ntok / 4, blk, 0, stream>>>(bufC, pos1, pos2, W_pos, W_bias, bufA);
    // o = att_out @ Wo + bo
    gemm_areg<2, false, true, false><<<M / 128, blk, 0, stream>>>(bufA, WoT, bo, bufC);
    // h1 = LN(o + t)
    ln_kernel<false><<<M / 4, blk, 0, stream>>>(bufC, bufB, g1, b1, bufA);
    // f = silu(h1 @ W_ff1)
    gemm_areg<8, false, false, true><<<M / 128, blk, 0, stream>>>(bufA, Wff1T, nullptr, bufC);
    // f2 = f @ W_ff2   (wide: full N per block, A read once)
    gemm_wide<<<M / 128, blk, 0, stream>>>(bufC, Wff2T, bufB);
    // out = LN(f2 + h1) -> fp32
    ln_kernel<true><<<M / 4, blk, 0, stream>>>(bufB, bufA, g2, b2, d_out);
}

// Round 3
// 885.975 us; speedup vs baseline: 1.0461x; 1.0461x over previous
//
#include <hip/hip_runtime.h>
#include <cstdint>
#include <cstddef>

typedef unsigned short ushort_t;
typedef __attribute__((ext_vector_type(8))) short short8;
typedef __attribute__((ext_vector_type(4))) short short4v;
typedef __attribute__((ext_vector_type(4))) float floatx4;

__device__ __forceinline__ float b2f(ushort_t u) {
    unsigned v = ((unsigned)u) << 16;
    return __builtin_bit_cast(float, v);
}
__device__ __forceinline__ float b2fs(short s) { return b2f((ushort_t)s); }
__device__ __forceinline__ ushort_t f2b(float f) {
    unsigned u = __builtin_bit_cast(unsigned, f);
    u += 0x7fffu + ((u >> 16) & 1u);   // RNE
    return (ushort_t)(u >> 16);
}

// async global->LDS, 16B per lane; lds base must be wave-uniform (HW adds lane*16)
__device__ __forceinline__ void load_lds16(const ushort_t* g, ushort_t* l) {
    __builtin_amdgcn_global_load_lds(
        (const __attribute__((address_space(1))) void*)g,
        (__attribute__((address_space(3))) void*)l, 16, 0, 0);
}

// ---------------------------------------------------------------------------
// Strip GEMM, K=256, A panel in registers. B double-buffered as 64-col x 256-k
// half-tiles (2 x 32KB LDS), counted-vmcnt pipeline. Epilogue: per-wave
// private 4KB LDS transpose (s16 ^= (row>>1)&3 swizzle) -> coalesced 16B/lane
// stores, 64B full-line segments per row (was 32B scatter = half-wasted
// DRAM bursts). No extra barriers (quadrant is wave-private).
// ---------------------------------------------------------------------------
template <int NT, bool A_F32, bool HAS_BIAS, bool DO_SILU>
__global__ __launch_bounds__(256, 2) void gemm_areg(
    const void* __restrict__ Ap, const ushort_t* __restrict__ BT,
    const float* __restrict__ bias, ushort_t* __restrict__ out)
{
    constexpr int K = 256;
    constexpr int ldN = NT * 128;
    constexpr int NH = NT * 2;                          // 64-col halves
    __shared__ __align__(16) ushort_t Bs[2][64 * 256];  // 2 x 32 KB, swizzled
    __shared__ __align__(16) ushort_t Fs[4 * 2048];     // 4 x 4 KB epilogue scratch

    const int tid = threadIdx.x;
    const int w = tid >> 6, lane = tid & 63;
    const int wm = w >> 1, wn = w & 1;
    const int quad = lane >> 4, r = lane & 15;
    const size_t m0 = (size_t)blockIdx.x * 128;
    ushort_t* Fw = Fs + w * 2048;                       // wave-private 4 KB

    // staging constants: 8 insts/wave cover 16 rows (2 rows per inst)
    const int srow_off = w * 2 + (lane >> 5);           // == row & 7
    const int sslot = (lane & 31) ^ srow_off;
    const int rsw = (r & 7) << 3;                       // read-side XOR (ushorts)

#define STAGE_H(h)                                                        \
    {                                                                     \
        const int h_ = (h);                                               \
        _Pragma("unroll")                                                 \
        for (int i_ = 0; i_ < 8; ++i_) {                                  \
            int row_ = i_ * 8 + srow_off;                                 \
            load_lds16(BT + (size_t)(h_ * 64 + row_) * K + sslot * 8,     \
                       &Bs[h_ & 1][(i_ * 8 + w * 2) * 256]);              \
        }                                                                 \
    }

    STAGE_H(0);

    // ---- A panel -> registers (rows wm*64+mt*16+r, k = kk*32+quad*8) ----
    short8 af[4][8];
    if (A_F32) {
        const float* A = (const float*)Ap;
#pragma unroll
        for (int mt = 0; mt < 4; ++mt) {
            const float* rp = A + (m0 + wm * 64 + mt * 16 + r) * K + quad * 8;
#pragma unroll
            for (int kk = 0; kk < 8; ++kk) {
                float4 a = *(const float4*)(rp + kk * 32);
                float4 b = *(const float4*)(rp + kk * 32 + 4);
                short8 o;
                o[0] = (short)f2b(a.x); o[1] = (short)f2b(a.y);
                o[2] = (short)f2b(a.z); o[3] = (short)f2b(a.w);
                o[4] = (short)f2b(b.x); o[5] = (short)f2b(b.y);
                o[6] = (short)f2b(b.z); o[7] = (short)f2b(b.w);
                af[mt][kk] = o;
            }
        }
    } else {
        const ushort_t* A = (const ushort_t*)Ap;
#pragma unroll
        for (int mt = 0; mt < 4; ++mt) {
            const ushort_t* rp = A + (m0 + wm * 64 + mt * 16 + r) * K + quad * 8;
#pragma unroll
            for (int kk = 0; kk < 8; ++kk)
                af[mt][kk] = *(const short8*)(rp + kk * 32);
        }
    }

    asm volatile("s_waitcnt vmcnt(0)" ::: "memory");
    __builtin_amdgcn_s_barrier();

    for (int p = 0; p < NH; ++p) {
        if (p + 1 < NH) STAGE_H(p + 1);

        floatx4 acc[2][4];
#pragma unroll
        for (int nt = 0; nt < 2; ++nt)
#pragma unroll
            for (int mt = 0; mt < 4; ++mt)
#pragma unroll
                for (int rg = 0; rg < 4; ++rg) acc[nt][mt][rg] = 0.f;

#pragma unroll
        for (int kk = 0; kk < 8; ++kk) {
            const int koff = (kk * 32 + quad * 8) ^ rsw;
#pragma unroll
            for (int nt = 0; nt < 2; ++nt) {
                int cl = wn * 32 + nt * 16 + r;          // cl&7 == r&7
                short8 bf_ = *(const short8*)(&Bs[p & 1][cl * 256 + koff]);
#pragma unroll
                for (int mt = 0; mt < 4; ++mt)
                    acc[nt][mt] = __builtin_amdgcn_mfma_f32_16x16x32_bf16(
                        bf_, af[mt][kk], acc[nt][mt], 0, 0, 0);
            }
        }
        // ---- epilogue: pack quadrant (64r x 32c) into wave-private LDS ----
        // lane (quad,r) holds row mt*16+r, cols nt*16+quad*4+{0..3}
#pragma unroll
        for (int nt = 0; nt < 2; ++nt) {
            const int colb = p * 64 + wn * 32 + nt * 16 + quad * 4;
            float b4[4] = {0.f, 0.f, 0.f, 0.f};
            if (HAS_BIAS) {
                float4 bb = *(const float4*)(bias + colb);
                b4[0] = bb.x; b4[1] = bb.y; b4[2] = bb.z; b4[3] = bb.w;
            }
#pragma unroll
            for (int mt = 0; mt < 4; ++mt) {
                short4v ov;
#pragma unroll
                for (int rg = 0; rg < 4; ++rg) {
                    float v = acc[nt][mt][rg] + b4[rg];
                    if (DO_SILU) v = v / (1.f + __expf(-v));
                    ov[rg] = (short)f2b(v);
                }
                int row_l = mt * 16 + r;
                int s16 = (nt * 2 + (quad >> 1)) ^ ((r >> 1) & 3);
                *(short4v*)(Fw + row_l * 32 + s16 * 8 + (quad & 1) * 4) = ov;
            }
        }
        asm volatile("s_waitcnt lgkmcnt(0)" ::: "memory");
        // coalesced stores: 4 lanes/row, 16 rows x 64B per instr
#pragma unroll
        for (int i = 0; i < 4; ++i) {
            int row_l = i * 16 + (lane >> 2);
            int s16 = (lane & 3) ^ ((row_l >> 1) & 3);
            short8 val = *(const short8*)(Fw + row_l * 32 + s16 * 8);
            size_t row = m0 + wm * 64 + row_l;
            *(short8*)(out + row * ldN + p * 64 + wn * 32 + (lane & 3) * 8) = val;
        }
        // FIFO: [8 stage loads][bias loads retired by dep][4 stores]
        // vmcnt(4) leaves the 4 stores in flight, drains all stage loads.
        asm volatile("s_waitcnt vmcnt(4)" ::: "memory");
        __builtin_amdgcn_s_barrier();
    }
#undef STAGE_H
}

// ---------------------------------------------------------------------------
// Wide GEMM for FF2: K=1024, N=256. 32-k chunk double-buffer (2x8KB A,
// 2x16KB B), counted-pipeline. Epilogue via wave-private LDS transpose in
// 4 chunks of 32 cols -> 64B-segment coalesced stores.
// ---------------------------------------------------------------------------
__global__ __launch_bounds__(256, 2) void gemm_wide(
    const ushort_t* __restrict__ A, const ushort_t* __restrict__ BT,
    ushort_t* __restrict__ out)
{
    constexpr int K = 1024, N = 256;
    __shared__ __align__(16) ushort_t As[2][128 * 32];   // 2 x 8 KB
    __shared__ __align__(16) ushort_t Bs[2][256 * 32];   // 2 x 16 KB
    __shared__ __align__(16) ushort_t Fs[4 * 2048];      // 4 x 4 KB scratch

    const int tid = threadIdx.x;
    const int w = tid >> 6, lane = tid & 63;
    const int wm = w >> 1, wn = w & 1;
    const int quad = lane >> 4, r = lane & 15;
    const size_t m0 = (size_t)blockIdx.x * 128;
    ushort_t* Fw = Fs + w * 2048;

    // staging: one inst covers 16 rows x 64B; slot(16B) ^= row&3
    const int srow = lane >> 2;                    // 0..15
    const int sslot = (lane & 3) ^ (srow & 3);

#define STAGE_C(c)                                                        \
    {                                                                     \
        const int c_ = (c);                                               \
        _Pragma("unroll")                                                 \
        for (int i_ = 0; i_ < 2; ++i_) {                                  \
            int rb_ = (w * 2 + i_) * 16;                                  \
            load_lds16(A + (m0 + rb_ + srow) * K + c_ * 32 + sslot * 8,   \
                       &As[c_ & 1][rb_ * 32]);                            \
        }                                                                 \
        _Pragma("unroll")                                                 \
        for (int i_ = 0; i_ < 4; ++i_) {                                  \
            int rb_ = (w * 4 + i_) * 16;                                  \
            load_lds16(BT + (size_t)(rb_ + srow) * K + c_ * 32 + sslot * 8,\
                       &Bs[c_ & 1][rb_ * 32]);                            \
        }                                                                 \
    }

    floatx4 acc[8][4];
#pragma unroll
    for (int nt = 0; nt < 8; ++nt)
#pragma unroll
        for (int mt = 0; mt < 4; ++mt)
#pragma unroll
            for (int rg = 0; rg < 4; ++rg) acc[nt][mt][rg] = 0.f;

    STAGE_C(0);
    asm volatile("s_waitcnt vmcnt(0)" ::: "memory");
    __builtin_amdgcn_s_barrier();

    const int ko = (quad ^ (r & 3)) * 8;           // swizzled 32-k slot

    for (int c = 0; c < K / 32; ++c) {
        if (c + 1 < K / 32) STAGE_C(c + 1);

        short8 af_[4];
#pragma unroll
        for (int mt = 0; mt < 4; ++mt)
            af_[mt] = *(const short8*)(&As[c & 1][(wm * 64 + mt * 16 + r) * 32 + ko]);
#pragma unroll
        for (int nt = 0; nt < 8; ++nt) {
            short8 bf_ = *(const short8*)(&Bs[c & 1][(wn * 128 + nt * 16 + r) * 32 + ko]);
#pragma unroll
            for (int mt = 0; mt < 4; ++mt)
                acc[nt][mt] = __builtin_amdgcn_mfma_f32_16x16x32_bf16(
                    bf_, af_[mt], acc[nt][mt], 0, 0, 0);
        }
        asm volatile("s_waitcnt vmcnt(0)" ::: "memory");
        __builtin_amdgcn_s_barrier();
    }
#undef STAGE_C

    // epilogue: 4 chunks of 32 cols through wave-private LDS transpose
#pragma unroll
    for (int ch = 0; ch < 4; ++ch) {
        if (ch) asm volatile("s_waitcnt lgkmcnt(0)" ::: "memory");
#pragma unroll
        for (int nt2 = 0; nt2 < 2; ++nt2) {
            const int nt = ch * 2 + nt2;
#pragma unroll
            for (int mt = 0; mt < 4; ++mt) {
                short4v ov;
#pragma unroll
                for (int rg = 0; rg < 4; ++rg) ov[rg] = (short)f2b(acc[nt][mt][rg]);
                int row_l = mt * 16 + r;
                int s16 = (nt2 * 2 + (quad >> 1)) ^ ((r >> 1) & 3);
                *(short4v*)(Fw + row_l * 32 + s16 * 8 + (quad & 1) * 4) = ov;
            }
        }
        asm volatile("s_waitcnt lgkmcnt(0)" ::: "memory");
#pragma unroll
        for (int i = 0; i < 4; ++i) {
            int row_l = i * 16 + (lane >> 2);
            int s16 = (lane & 3) ^ ((row_l >> 1) & 3);
            short8 val = *(const short8*)(Fw + row_l * 32 + s16 * 8);
            size_t row = m0 + wm * 64 + row_l;
            *(short8*)(out + row * N + wn * 128 + ch * 32 + (lane & 3) * 8) = val;
        }
    }
}

// ---------------------------------------------------------------------------
// LayerNorm over rows of 256: out = LN(y [+ res]) * g + b.  1 wave per row.
// ---------------------------------------------------------------------------
template <bool OUT_F32>
__global__ __launch_bounds__(256) void ln_kernel(
    const ushort_t* __restrict__ y, const ushort_t* __restrict__ res,
    const float* __restrict__ g, const float* __restrict__ b,
    void* __restrict__ outv)
{
    const int w = threadIdx.x >> 6;
    const int lane = threadIdx.x & 63;
    const size_t row = (size_t)blockIdx.x * 4 + w;
    const size_t base = row * 256 + lane * 4;

    short4v vy = *(const short4v*)(y + base);
    float v[4];
#pragma unroll
    for (int j = 0; j < 4; ++j) v[j] = b2fs(vy[j]);
    if (res) {
        short4v vr = *(const short4v*)(res + base);
#pragma unroll
        for (int j = 0; j < 4; ++j) v[j] += b2fs(vr[j]);
    }
    float s = v[0] + v[1] + v[2] + v[3];
    float sq = v[0] * v[0] + v[1] * v[1] + v[2] * v[2] + v[3] * v[3];
#pragma unroll
    for (int off = 32; off > 0; off >>= 1) {
        s += __shfl_xor(s, off, 64);
        sq += __shfl_xor(sq, off, 64);
    }
    float mean = s * (1.f / 256.f);
    float var = sq * (1.f / 256.f) - mean * mean;
    float rstd = rsqrtf(var + 1e-5f);
    if (OUT_F32) {
        float4 ov;
        int col = lane * 4;
        ov.x = (v[0] - mean) * rstd * g[col + 0] + b[col + 0];
        ov.y = (v[1] - mean) * rstd * g[col + 1] + b[col + 1];
        ov.z = (v[2] - mean) * rstd * g[col + 2] + b[col + 2];
        ov.w = (v[3] - mean) * rstd * g[col + 3] + b[col + 3];
        *(float4*)((float*)outv + base) = ov;
    } else {
        short4v ov;
#pragma unroll
        for (int j = 0; j < 4; ++j) {
            int col = lane * 4 + j;
            float o = (v[j] - mean) * rstd * g[col] + b[col];
            ov[j] = (short)f2b(o);
        }
        *(short4v*)((ushort_t*)outv + base) = ov;
    }
}

// ---------------------------------------------------------------------------
// Attention: one wave per token (8 positions x 8 heads x d=32).
// ---------------------------------------------------------------------------
__global__ __launch_bounds__(256) void attn_kernel(
    const ushort_t* __restrict__ qkv,
    const float* __restrict__ pos1, const float* __restrict__ pos2,
    const float* __restrict__ Wpos, const float* __restrict__ Wbias,
    ushort_t* __restrict__ att_out)
{
    __shared__ __align__(16) ushort_t qkv_s[4][8 * 768];
    __shared__ float bias_s[4][8][8];
    __shared__ float wpos_s[128];
    __shared__ float wbias_s[256];

    const int tid = threadIdx.x;
    if (tid < 128) wpos_s[tid] = Wpos[tid];
    wbias_s[tid] = Wbias[tid];

    const int w = tid >> 6;
    const int lane = tid & 63;
    const int tok = blockIdx.x * 4 + w;

    const ushort_t* src = qkv + (size_t)tok * 8 * 768;
    for (int c = lane; c < 768; c += 64)
        *(short8*)(qkv_s[w] + c * 8) = *(const short8*)(src + c * 8);
    __syncthreads();

    {   // positional bias: lane = j*8 + h
        const int j = lane >> 3, h = lane & 7;
        const size_t pbase = ((size_t)tok * 8 + j) * 2;
        float p0 = pos1[pbase], p1 = pos1[pbase + 1];
        float p2 = pos2[pbase], p3 = pos2[pbase + 1];
        float acc = 0.f;
#pragma unroll
        for (int p = 0; p < 32; ++p) {
            float e = p0 * wpos_s[p] + p1 * wpos_s[32 + p] + p2 * wpos_s[64 + p] + p3 * wpos_s[96 + p];
            e = e / (1.f + __expf(-e));
            acc += e * wbias_s[p * 8 + h];
        }
        bias_s[w][j][h] = acc;
    }
    __syncthreads();

    const int i = lane >> 3, h = lane & 7;
    const ushort_t* qrow = qkv_s[w] + i * 768 + h * 32;
    float q[32];
#pragma unroll
    for (int c = 0; c < 4; ++c) {
        short8 t8 = *(const short8*)(qrow + c * 8);
#pragma unroll
        for (int e = 0; e < 8; ++e) q[c * 8 + e] = b2fs(t8[e]);
    }
    float s[8];
#pragma unroll
    for (int jj = 0; jj < 8; ++jj) {
        const ushort_t* krow = qkv_s[w] + jj * 768 + 256 + h * 32;
        float d = 0.f;
#pragma unroll
        for (int c = 0; c < 4; ++c) {
            short8 t8 = *(const short8*)(krow + c * 8);
#pragma unroll
            for (int e = 0; e < 8; ++e) d += q[c * 8 + e] * b2fs(t8[e]);
        }
        s[jj] = d * 0.17677669529663688f + bias_s[w][jj][h];
    }
    float mx = s[0];
#pragma unroll
    for (int jj = 1; jj < 8; ++jj) mx = fmaxf(mx, s[jj]);
    float l = 0.f;
#pragma unroll
    for (int jj = 0; jj < 8; ++jj) { s[jj] = __expf(s[jj] - mx); l += s[jj]; }
    float rl = 1.f / l;
    float o[32];
#pragma unroll
    for (int e = 0; e < 32; ++e) o[e] = 0.f;
#pragma unroll
    for (int jj = 0; jj < 8; ++jj) {
        float p = s[jj] * rl;
        const ushort_t* vrow = qkv_s[w] + jj * 768 + 512 + h * 32;
#pragma unroll
        for (int c = 0; c < 4; ++c) {
            short8 t8 = *(const short8*)(vrow + c * 8);
#pragma unroll
            for (int e = 0; e < 8; ++e) o[c * 8 + e] += p * b2fs(t8[e]);
        }
    }
    ushort_t* orow = att_out + ((size_t)tok * 8 + i) * 256 + h * 32;
#pragma unroll
    for (int c = 0; c < 4; ++c) {
        short8 t8;
#pragma unroll
        for (int e = 0; e < 8; ++e) t8[e] = (short)f2b(o[c * 8 + e]);
        *(short8*)(orow + c * 8) = t8;
    }
}

// ---------------------------------------------------------------------------
__global__ void transpose_kernel(const float* __restrict__ in,
                                 ushort_t* __restrict__ out, int K, int N)
{
    int idx = blockIdx.x * 256 + threadIdx.x;
    if (idx < K * N) {
        int k = idx / N, n = idx % N;
        out[n * K + k] = f2b(in[idx]);
    }
}

__global__ void pack_bias_kernel(const float* a, const float* b,
                                 const float* c, float* out)
{
    int t = blockIdx.x * 256 + threadIdx.x;
    if (t < 256) out[t] = a[t];
    else if (t < 512) out[t] = b[t - 256];
    else if (t < 768) out[t] = c[t - 512];
}

// ---------------------------------------------------------------------------
extern "C" void kernel_launch(void* const* d_in, const int* in_sizes, int n_in,
                              void* d_out, int out_size, void* d_ws, size_t ws_size,
                              hipStream_t stream)
{
    const float* x     = (const float*)d_in[0];
    const float* pos1  = (const float*)d_in[1];
    const float* pos2  = (const float*)d_in[2];
    const float* W_in  = (const float*)d_in[3];
    const float* g_in  = (const float*)d_in[4];
    const float* b_in  = (const float*)d_in[5];
    const float* Wq    = (const float*)d_in[6];
    const float* bq    = (const float*)d_in[7];
    const float* Wk    = (const float*)d_in[8];
    const float* bk    = (const float*)d_in[9];
    const float* Wv    = (const float*)d_in[10];
    const float* bv    = (const float*)d_in[11];
    const float* Wo    = (const float*)d_in[12];
    const float* bo    = (const float*)d_in[13];
    const float* W_pos = (const float*)d_in[14];
    const float* W_bias= (const float*)d_in[15];
    const float* W_ff1 = (const float*)d_in[16];
    const float* W_ff2 = (const float*)d_in[17];
    const float* g1    = (const float*)d_in[18];
    const float* b1    = (const float*)d_in[19];
    const float* g2    = (const float*)d_in[20];
    const float* b2    = (const float*)d_in[21];

    const int M = in_sizes[0] / 256;   // 131072 rows (b,n,nh)
    const int ntok = M / 8;            // 16384 tokens

    // ws: 2MB header (bf16 weights^T + fp32 qkv bias) then big buffers
    ushort_t* ws    = (ushort_t*)d_ws;
    ushort_t* WinT  = ws;              // 256x256
    ushort_t* WqkvT = ws + 65536;      // 768x256
    ushort_t* WoT   = ws + 262144;     // 256x256
    ushort_t* Wff1T = ws + 327680;     // 1024x256
    ushort_t* Wff2T = ws + 589824;     // 256x1024
    float*    bqkv  = (float*)(ws + 851968);                    // 768 fp32
    ushort_t* bufA  = (ushort_t*)((char*)d_ws + (2ull << 20));  // M*256
    ushort_t* bufB  = bufA + (size_t)M * 256;                   // M*256
    ushort_t* bufC  = bufB + (size_t)M * 256;                   // M*1024

    transpose_kernel<<<256, 256, 0, stream>>>(W_in, WinT, 256, 256);
    transpose_kernel<<<256, 256, 0, stream>>>(Wq, WqkvT, 256, 256);
    transpose_kernel<<<256, 256, 0, stream>>>(Wk, WqkvT + 65536, 256, 256);
    transpose_kernel<<<256, 256, 0, stream>>>(Wv, WqkvT + 131072, 256, 256);
    transpose_kernel<<<256, 256, 0, stream>>>(Wo, WoT, 256, 256);
    transpose_kernel<<<1024, 256, 0, stream>>>(W_ff1, Wff1T, 256, 1024);
    transpose_kernel<<<1024, 256, 0, stream>>>(W_ff2, Wff2T, 1024, 256);
    pack_bias_kernel<<<3, 256, 0, stream>>>(bq, bk, bv, bqkv);

    dim3 blk(256);
    // y = x @ W_in      (fp32 A fused-converted into A-registers)
    gemm_areg<2, true, false, false><<<M / 128, blk, 0, stream>>>(x, WinT, nullptr, bufA);
    // t = LN(y)
    ln_kernel<false><<<M / 4, blk, 0, stream>>>(bufA, nullptr, g_in, b_in, bufB);
    // qkv = t @ [Wq|Wk|Wv] + [bq|bk|bv]
    gemm_areg<6, false, true, false><<<M / 128, blk, 0, stream>>>(bufB, WqkvT, bqkv, bufC);
    // att_out = attention(qkv, pos)
    attn_kernel<<<ntok / 4, blk, 0, stream>>>(bufC, pos1, pos2, W_pos, W_bias, bufA);
    // o = att_out @ Wo + bo
    gemm_areg<2, false, true, false><<<M / 128, blk, 0, stream>>>(bufA, WoT, bo, bufC);
    // h1 = LN(o + t)
    ln_kernel<false><<<M / 4, blk, 0, stream>>>(bufC, bufB, g1, b1, bufA);
    // f = silu(h1 @ W_ff1)
    gemm_areg<8, false, false, true><<<M / 128, blk, 0, stream>>>(bufA, Wff1T, nullptr, bufC);
    // f2 = f @ W_ff2   (wide: full N per block, A read once)
    gemm_wide<<<M / 128, blk, 0, stream>>>(bufC, Wff2T, bufB);
    // out = LN(f2 + h1) -> fp32
    ln_kernel<true><<<M / 4, blk, 0, stream>>>(bufB, bufA, g2, b2, d_out);
}